// Round 11
// baseline (1332.811 us; speedup 1.0000x reference)
//
#include <hip/hip_runtime.h>
#include <cstdint>
#include <cstddef>

// CTC-CRF logZ: S=1024, NZ=5. Linear-domain A' = 2^-L * sum_j E_j*A[pred_j],
// E = exp2(K*m) PRECOMPUTED by 192 producer blocks into an fp16 ring buffer
// in d_ws (W slots/batch, 10KB/step: 8KB "A" region = 4 halves/thread +
// 2KB "B" region = 1 half/thread). Consumers (32 blocks, 1024 thr) run the
// recursion with NO transcendentals: 5 fma + cvt + dpp + exact pow2 scale
// (deadbeat renorm: scale applied after the sum). 32 warmer blocks keep the
// E stream warm in the consumer's XCD L2 (R9-proven mechanism, +16%).
// Sync: per-16-step chunk flags, agent-scope atomics (R9-proven cross-XCD);
// producer release-store (wbl2) publishes E; consumer/warmer ACQUIRE
// (buffer_inv) only at ring-wrap boundaries kills stale-L2 ring lines.
// Producers throttled to [p, p+W) via consumer progress; consumers never
// exceed flagged chunks -> timing-independent correctness. Fallback to the
// exact R9 kernel when ws_size can't hold a W=32 ring.

#define NB 32
#define SD 1024
#define CD 5120
#define DONE_S 0x7fffffff
#define NWARM 40
#define AHEAD 24
#define CHUNK 8

typedef float f4a __attribute__((ext_vector_type(4), aligned(4)));
typedef unsigned short u16;
typedef u16 us4 __attribute__((ext_vector_type(4), aligned(8)));

__device__ __forceinline__ float fexp2(float x) { return __builtin_amdgcn_exp2f(x); }
__device__ __forceinline__ float flog2(float x) { return __builtin_amdgcn_logf(x); }
__device__ __forceinline__ u16 f2h(float f) { _Float16 h = (_Float16)f; return __builtin_bit_cast(u16, h); }
__device__ __forceinline__ float h2f(u16 b) { return (float)__builtin_bit_cast(_Float16, b); }

template <int CTRL>
__device__ __forceinline__ float dppq(float v) {
  return __int_as_float(
      __builtin_amdgcn_update_dpp(0, __float_as_int(v), CTRL, 0xF, 0xF, true));
}

// ws layout (ints): [0..2047] prog (n*64), [2048..6143] flags (n*128+c),
// byte 65536+: E ring. EA = 32*W*4096 u16, then EB = 32*W*1024 u16.
__global__ void init_ws(int* ws) {
  const int i = threadIdx.x;
#pragma unroll
  for (int k = 0; k < 6; ++k) ws[i + (k << 10)] = 0;
  __syncthreads();
  if (i == 0)
    __hip_atomic_store(&ws[6144], 1, __ATOMIC_RELEASE, __HIP_MEMORY_SCOPE_AGENT);
}

// ---------------------------------------------------------------- MODE1 ----
__global__ void __launch_bounds__(1024) ctc_fused(const float* __restrict__ scores,
                                                  float* __restrict__ out,
                                                  int* __restrict__ ws, int T, int W) {
  __shared__ float ap[2 * SD];
  __shared__ float red[16];
  __shared__ float pad[19456];   // force 1 block/CU
  __shared__ int pmsg;

  const int bid = blockIdx.x;
  const int u = threadIdx.x;
  if (T < 0) { pad[u] = 1.f; out[0] = pad[u ^ 1]; }

  int* prog = ws;
  int* flags = ws + 2048;
  u16* EA = (u16*)((char*)ws + 65536);
  u16* EB = EA + (size_t)32 * W * 4096;
  const size_t tstr = (size_t)NB * CD;
  const int wmask = W - 1;
  const int NC = (T + 15) >> 4;

  if (bid >= 64) {
    // ------------------------------ producer ------------------------------
    const int h = bid - 64;
    const int n = h & 31;
    const int k = h >> 5;                    // 0..5
    u16* EAw = EA + (size_t)n * W * 4096;
    u16* EBw = EB + (size_t)n * W * 1024;
    const float K = 1.44269504088896340736f;
    for (int c = k; (c << 4) < T; c += 6) {
      const int t0 = c << 4;
      for (;;) {
        if (u == 0) {
          int p = __hip_atomic_load(&prog[n << 6], __ATOMIC_RELAXED, __HIP_MEMORY_SCOPE_AGENT);
          pmsg = (p == DONE_S) ? 2 : ((t0 + 15 < p + W) ? 1 : 0);
        }
        __syncthreads();
        const int st = pmsg;
        __syncthreads();
        if (st == 2) return;
        if (st == 1) break;
        __builtin_amdgcn_s_sleep(16);
      }
      const float* sp = scores + (size_t)n * CD + (size_t)t0 * tstr + (size_t)u * 5;
      const int lim = (T - t0 < 16) ? (T - t0) : 16;
#define PEMIT(RA, RB, S)                                                     \
  {                                                                          \
    const int slot = (t0 + (S)) & wmask;                                     \
    us4 o;                                                                   \
    o.x = f2h(fexp2(RA.x * K)); o.y = f2h(fexp2(RA.y * K));                  \
    o.z = f2h(fexp2(RA.z * K)); o.w = f2h(fexp2(RA.w * K));                  \
    __builtin_nontemporal_store(o, (us4*)(EAw + (size_t)slot * 4096 + (u << 2))); \
    __builtin_nontemporal_store(f2h(fexp2(RB * K)), EBw + (size_t)slot * 1024 + u); \
  }
      f4a ra0, ra1; float rb0, rb1;
      ra0 = *(const f4a*)sp; rb0 = sp[4]; sp += tstr;
      if (lim > 1) { ra1 = *(const f4a*)sp; rb1 = sp[4]; }
      sp += tstr;
      int s = 0;
      for (;;) {
        PEMIT(ra0, rb0, s);
        if (s + 2 < lim) { ra0 = *(const f4a*)sp; rb0 = sp[4]; sp += tstr; }
        if (++s >= lim) break;
        PEMIT(ra1, rb1, s);
        if (s + 2 < lim) { ra1 = *(const f4a*)sp; rb1 = sp[4]; sp += tstr; }
        if (++s >= lim) break;
      }
#undef PEMIT
      __syncthreads();                       // all waves' stores drained
      if (u == 0)
        __hip_atomic_store(&flags[(n << 7) + c], 1, __ATOMIC_RELEASE, __HIP_MEMORY_SCOPE_AGENT);
    }
    return;
  }

  if (bid >= NB) {
    // ------------------------------- warmer -------------------------------
    const int n = bid - NB;
    const char* EAb = (const char*)(EA + (size_t)n * W * 4096);
    const char* EBb = (const char*)(EB + (size_t)n * W * 1024);
    int acc = 0;
    for (int cb = 0; cb < NC; ++cb) {
      for (;;) {
        if (u == 0) {
          int f = __hip_atomic_load(&flags[(n << 7) + cb], __ATOMIC_RELAXED, __HIP_MEMORY_SCOPE_AGENT);
          int p = __hip_atomic_load(&prog[n << 6], __ATOMIC_RELAXED, __HIP_MEMORY_SCOPE_AGENT);
          pmsg = (p == DONE_S) ? 2 : ((f && ((cb << 4) < p + NWARM)) ? 1 : 0);
        }
        __syncthreads();
        const int st = pmsg;
        __syncthreads();
        if (st == 2) goto wdone;
        if (st == 1) break;
        __builtin_amdgcn_s_sleep(8);
      }
      if ((((cb) << 4) & wmask) == 0) {      // ring-wrap: invalidate stale L2
        if (u == 0)
          (void)__hip_atomic_load(&flags[(n << 7) + cb], __ATOMIC_ACQUIRE, __HIP_MEMORY_SCOPE_AGENT);
        __syncthreads();
      }
#pragma unroll
      for (int k = 0; k < 3; ++k) {
        const int idx = u + (k << 10);
        if (idx < 2048) {
          const int st = idx >> 7, ln = idx & 127;
          const int slot = ((cb << 4) + st) & wmask;
          acc += *(const int*)(EAb + (size_t)slot * 8192 + ln * 64);
        } else if (idx < 2560) {
          const int i2 = idx - 2048;
          const int st = i2 >> 5, ln = i2 & 31;
          const int slot = ((cb << 4) + st) & wmask;
          acc += *(const int*)(EBb + (size_t)slot * 2048 + ln * 64);
        }
      }
    }
  wdone:
    asm volatile("" ::"v"(acc));
    return;
  }

  // ------------------------------- consumer -------------------------------
  {
    const int n = bid;
    const int lane = u & 63;
    const int wid = u >> 6;
    const int p = u >> 2, c = u & 3;
    const int rdoff = (c << 8) | (p ^ (c << 3));
    const int wroff = u ^ ((u & 0x300) >> 5);

    ap[u] = 1.f; ap[SD + u] = 1.f;
    float a_cur = 1.f;
    int cacc = 0;
    const float LN2 = 0.69314718055994530942f;

    const u16* EAr = EA + (size_t)n * W * 4096;
    const u16* EBr = EB + (size_t)n * W * 1024;

    auto wait_flag = [&](int cidx, bool acq) {
      for (;;) {
        if (u == 0)
          pmsg = __hip_atomic_load(&flags[(n << 7) + cidx], __ATOMIC_RELAXED, __HIP_MEMORY_SCOPE_AGENT);
        asm volatile("s_waitcnt lgkmcnt(0)\n\ts_barrier" ::: "memory");
        const int f = pmsg;
        asm volatile("s_barrier" ::: "memory");
        if (f) break;
        __builtin_amdgcn_s_sleep(2);
      }
      if (acq) {
        if (u == 0)
          (void)__hip_atomic_load(&flags[(n << 7) + cidx], __ATOMIC_ACQUIRE, __HIP_MEMORY_SCOPE_AGENT);
        asm volatile("s_barrier" ::: "memory");
      }
    };

    auto LD1 = [&](int tt, us4& qa, u16& qb) {
      const int tc = tt < T ? tt : T - 1;
      const int slot = tc & wmask;
      qa = *(const us4*)(EAr + (size_t)slot * 4096 + (u << 2));
      qb = EBr[(size_t)slot * 1024 + u];
    };

    auto CP = [&](int t, const us4& qa, u16 qb) {
      const int rb = ((t + 1) & 1) << 10;
      const float vr = ap[rb + rdoff];
      const float R = ap[rb];
      const float p0 = dppq<0x00>(vr);
      const float p1 = dppq<0x55>(vr);
      const float p2 = dppq<0xAA>(vr);
      const float p3 = dppq<0xFF>(vr);
      float s = h2f(qa.x) * a_cur;
      s = __builtin_fmaf(h2f(qa.y), p0, s);
      s = __builtin_fmaf(h2f(qa.z), p1, s);
      s = __builtin_fmaf(h2f(qa.w), p2, s);
      s = __builtin_fmaf(h2f(qb),   p3, s);
      const int eR = (__float_as_int(R) >> 23) & 0xFF;   // deadbeat renorm
      cacc += eR - 127;
      s *= __int_as_float((254 - eR) << 23);
      a_cur = s;
      ap[((t & 1) << 10) + wroff] = s;
      if (((t & 3) == 0) && (u == 0))
        __hip_atomic_store(&prog[n << 6], t, __ATOMIC_RELAXED, __HIP_MEMORY_SCOPE_AGENT);
      asm volatile("s_waitcnt lgkmcnt(0)\n\ts_barrier" ::: "memory");
    };

    us4 qa0, qa1, qa2, qa3; u16 qb0, qb1, qb2, qb3;
    wait_flag(0, true);                      // startup acquire (replay safety)
    LD1(0, qa0, qb0); LD1(1, qa1, qb1); LD1(2, qa2, qb2); LD1(3, qa3, qb3);
    asm volatile("s_waitcnt lgkmcnt(0)\n\ts_barrier" ::: "memory");  // ap init

    int t = 0;
    for (int cb = 0; cb < NC; ++cb) {
      if (cb + 1 < NC) {
        const bool wrap = ((((cb + 1) << 4) & wmask) == 0);
        wait_flag(cb + 1, wrap);
      }
#define STEP(SS) if (t < T) { CP(t, qa##SS, qb##SS); LD1(t + 4, qa##SS, qb##SS); ++t; }
      STEP(0) STEP(1) STEP(2) STEP(3)
      STEP(0) STEP(1) STEP(2) STEP(3)
      STEP(0) STEP(1) STEP(2) STEP(3)
      STEP(0) STEP(1) STEP(2) STEP(3)
#undef STEP
    }

    if (u == 0)
      __hip_atomic_store(&prog[n << 6], DONE_S, __ATOMIC_RELAXED, __HIP_MEMORY_SCOPE_AGENT);

    float v = a_cur;
#pragma unroll
    for (int d = 1; d < 64; d <<= 1) v += __shfl_xor(v, d, 64);
    if (lane == 0) red[wid] = v;
    __syncthreads();
    if (u == 0) {
      float ssum = red[0];
#pragma unroll
      for (int i = 1; i < 16; ++i) ssum += red[i];
      out[n] = LN2 * ((float)cacc + flog2(ssum));
    }
  }
}

// ------------------------------ MODE0 = exact R9 ----------------------------
__global__ void __launch_bounds__(1024) ctc_base(const float* __restrict__ scores,
                                                 float* __restrict__ out,
                                                 int* __restrict__ prog, int T) {
  __shared__ float ap[2 * SD];
  __shared__ float red[16];
  __shared__ float pad[19456];
  __shared__ int pmsg;

  const int bid = blockIdx.x;
  const int u = threadIdx.x;
  if (T < 0) { pad[u] = 1.f; out[0] = pad[u ^ 1]; }
  const size_t tstr = (size_t)NB * CD;

  if (bid >= NB) {
    const int h = bid - NB;
    const int n = h & 31;
    const int parity = h >> 5;
    const float* base = scores + (size_t)n * CD;
    float acc = 0.f;
    for (int c = parity; c * CHUNK < T; c += 2) {
      const int t0 = c * CHUNK;
      int p;
      for (;;) {
        if (u == 0)
          pmsg = __hip_atomic_load(&prog[n * 64], __ATOMIC_RELAXED, __HIP_MEMORY_SCOPE_AGENT);
        __syncthreads();
        p = pmsg;
        __syncthreads();
        if (p == DONE_S || t0 < p + AHEAD) break;
        __builtin_amdgcn_s_sleep(8);
      }
      if (p == DONE_S) break;
      if (t0 + CHUNK <= p) continue;
      if (u < 320) {
        const float* cb = base + (size_t)t0 * tstr + (size_t)u * 16;
        const int lim = (T - t0 < CHUNK) ? (T - t0) : CHUNK;
        for (int s = 0; s < lim; ++s) { acc += *cb; cb += tstr; }
      }
    }
    asm volatile("" ::"v"(acc));
    return;
  }

  const int n = bid;
  const int lane = u & 63;
  const int wid = u >> 6;
  const int p = u >> 2, c = u & 3;
  const int rdoff = (c << 8) | (p ^ (c << 3));
  const int wroff = u ^ ((u & 0x300) >> 5);

  ap[u] = 1.f; ap[SD + u] = 1.f;
  float a_cur = 1.f;
  float nLf = 0.f;
  int Lnext = 0, cacc = 0;
  const float K = 1.44269504088896340736f;
  const float LN2 = 0.69314718055994530942f;
  const float* sn = scores + (size_t)n * CD + (size_t)u * 5;
  const size_t str4 = 4 * tstr;

  auto CP = [&](int t, const f4a& qa, float qb) {
    const int rb = ((t + 1) & 1) * SD;
    const float vr = ap[rb + rdoff];
    const float R = ap[rb];
    const float p0 = dppq<0x00>(vr);
    const float p1 = dppq<0x55>(vr);
    const float p2 = dppq<0xAA>(vr);
    const float p3 = dppq<0xFF>(vr);
    float e0 = fexp2(__builtin_fmaf(qa.x, K, nLf));
    float e1 = fexp2(__builtin_fmaf(qa.y, K, nLf));
    float e2 = fexp2(__builtin_fmaf(qa.z, K, nLf));
    float e3 = fexp2(__builtin_fmaf(qa.w, K, nLf));
    float e4 = fexp2(__builtin_fmaf(qb,   K, nLf));
    float s = e0 * a_cur;
    s = __builtin_fmaf(e1, p0, s);
    s = __builtin_fmaf(e2, p1, s);
    s = __builtin_fmaf(e3, p2, s);
    s = __builtin_fmaf(e4, p3, s);
    a_cur = s;
    cacc += Lnext;
    ap[(t & 1) * SD + wroff] = s;
    const int xb = ((__float_as_int(R) >> 23) & 0xFF) - 127;
    Lnext = xb >> 2;
    nLf = (float)(-Lnext);
    if (((t & 3) == 0) && (u == 0))
      __hip_atomic_store(&prog[n * 64], t, __ATOMIC_RELAXED, __HIP_MEMORY_SCOPE_AGENT);
    asm volatile("s_waitcnt lgkmcnt(0)\n\ts_barrier" ::: "memory");
  };

#define PRO(cc)                                                             \
  const float* P##cc = sn + (size_t)((cc) < T ? (cc) : T - 1) * tstr;       \
  f4a qa##cc = *(const f4a*)P##cc;                                          \
  float qb##cc = P##cc[4];                                                  \
  P##cc += str4;
  PRO(0) PRO(1) PRO(2) PRO(3)
#undef PRO
  __syncthreads();
#define RL(cc)                                                              \
  qa##cc = *(const f4a*)P##cc;                                              \
  qb##cc = P##cc[4];                                                        \
  P##cc += str4;
  int t = 0;
  for (; t + 8 <= T; t += 4) {
    CP(t + 0, qa0, qb0); RL(0)
    CP(t + 1, qa1, qb1); RL(1)
    CP(t + 2, qa2, qb2); RL(2)
    CP(t + 3, qa3, qb3); RL(3)
  }
#undef RL
#define EPI1(cc)                                                            \
  if (t + (cc) < T) {                                                       \
    CP(t + (cc), qa##cc, qb##cc);                                           \
    if (t + 4 + (cc) < T) { qa##cc = *(const f4a*)P##cc; qb##cc = P##cc[4]; }\
  }
  EPI1(0) EPI1(1) EPI1(2) EPI1(3)
#undef EPI1
  t += 4;
#define EPI2(cc) if (t + (cc) < T) CP(t + (cc), qa##cc, qb##cc);
  EPI2(0) EPI2(1) EPI2(2) EPI2(3)
#undef EPI2

  if (u == 0)
    __hip_atomic_store(&prog[n * 64], DONE_S, __ATOMIC_RELAXED, __HIP_MEMORY_SCOPE_AGENT);

  float v = a_cur;
#pragma unroll
  for (int d = 1; d < 64; d <<= 1) v += __shfl_xor(v, d, 64);
  if (lane == 0) red[wid] = v;
  __syncthreads();
  if (u == 0) {
    float ssum = red[0];
#pragma unroll
    for (int i = 1; i < 16; ++i) ssum += red[i];
    out[n] = LN2 * ((float)cacc + flog2(ssum));
  }
}

extern "C" void kernel_launch(void* const* d_in, const int* in_sizes, int n_in,
                              void* d_out, int out_size, void* d_ws, size_t ws_size,
                              hipStream_t stream) {
  const float* scores = (const float*)d_in[0];
  float* out = (float*)d_out;
  int* ws = (int*)d_ws;
  const long long tot = (long long)in_sizes[0];
  const int T = (int)(tot / ((long long)NB * CD));

  int W = 0;
  for (int w = 128; w >= 32; w >>= 1) {
    const size_t need = 65536 + (size_t)32 * w * 10240;
    if (ws_size >= need) { W = w; break; }
  }
  init_ws<<<dim3(1), dim3(1024), 0, stream>>>(ws);
  if (W >= 32 && T <= 2048 && T >= 20) {
    ctc_fused<<<dim3(256), dim3(1024), 0, stream>>>(scores, out, ws, T, W);
  } else {
    ctc_base<<<dim3(96), dim3(1024), 0, stream>>>(scores, out, ws, T);
  }
}